// Round 1
// baseline (7259.866 us; speedup 1.0000x reference)
//
#include <hip/hip_runtime.h>

// GPT-2 forward, bf16-MFMA compute / f32 residual+softmax+LN.
// Round 1: correctness-first skeleton. One templated GEMM kernel (16x16x32 bf16
// MFMA, 2-barrier K-loop, LDS rows padded to 40 elems for <=2-way banks).

#define LL 12
#define DM 1024
#define NH 16
#define DHD 64
#define NV 50257
#define SQ 512
#define NB 4
#define DF 4096
#define MR (NB * SQ)  // 2048 rows

typedef short bf16x8 __attribute__((ext_vector_type(8)));
typedef float f32x4 __attribute__((ext_vector_type(4)));
typedef unsigned short u16;

__device__ __forceinline__ u16 f2b(float f) {  // f32 -> bf16 RNE
  unsigned u = __float_as_uint(f);
  u += 0x7fff + ((u >> 16) & 1);
  return (u16)(u >> 16);
}

#define BK 32
#define LSTR 40  // padded LDS row stride (bf16 elems): 80B -> 2-way bank alias max

// MODE: 0 = bf16 C out            (generic)
//       1 = residual: Cf32 += acc + bias   (Wo, W2 -> x)
//       2 = bf16 C = gelu(acc + bias)      (W1)
//       4 = scores: z=(b,h) batch, f32 C, masked-block early exit
//       5 = PV:     z=(b,h) batch, bf16 C into ctx slice (N=64 guard)
//       6 = f32 C out, N tail guard        (logits)
//       7 = fused QKV: B/C selected by blockIdx.y>>3; V written transposed
// BT: B stored [N,K] (contig-K rows); else [K,N] f32 weights (transpose-staged)
template <int MODE, bool BT, bool BBF16, int TBM, int TBN>
__global__ __launch_bounds__(256) void gemm_k(
    const u16* __restrict__ A, const void* __restrict__ Bp,
    const void* __restrict__ Bp2, const void* __restrict__ Bp3,
    void* __restrict__ Cp, void* __restrict__ Cp2, void* __restrict__ Cp3,
    const float* __restrict__ bias, int M, int N, int K, int lda, int ldb,
    int ldc) {
  int mt = blockIdx.x, nt = blockIdx.y, z = blockIdx.z;
  int sel = 0;
  if constexpr (MODE == 7) { sel = nt >> 3; nt &= 7; }
  int m0 = mt * TBM, n0 = nt * TBN;

  const u16* Ab = A;
  const u16* Bb16 = (const u16*)Bp;
  const float* Bbf = (const float*)Bp;
  size_t coff = 0;
  if constexpr (MODE == 4) {
    if (n0 >= m0 + TBM) return;  // fully-masked block: softmax never reads it
    int b = z >> 4, h = z & 15;
    Ab = A + ((size_t)b * SQ * DM + h * DHD);
    Bb16 = (const u16*)Bp + ((size_t)b * SQ * DM + h * DHD);
    coff = (size_t)z * SQ * SQ;
  }
  if constexpr (MODE == 5) {
    int b = z >> 4, h = z & 15;
    Ab = A + (size_t)z * SQ * SQ;
    Bb16 = (const u16*)Bp + ((size_t)b * DM + h * DHD) * (size_t)SQ;
    coff = (size_t)b * SQ * DM + h * DHD;
  }
  if constexpr (MODE == 7) {
    Bbf = sel == 0 ? (const float*)Bp
                   : sel == 1 ? (const float*)Bp2 : (const float*)Bp3;
  }

  __shared__ u16 As[TBM * LSTR];
  __shared__ u16 Bs[TBN * LSTR];

  int t = threadIdx.x;
  int lane = t & 63;
  int wave = t >> 6;
  int wm = wave >> 1, wn = wave & 1;  // 2x2 wave grid
  int lr = lane & 15, lk = (lane >> 4) * 8;
  constexpr int FM = TBM / 32, FN = TBN / 32;

  f32x4 acc[FM][FN];
#pragma unroll
  for (int i = 0; i < FM; ++i)
#pragma unroll
    for (int j = 0; j < FN; ++j) acc[i][j] = (f32x4){0.f, 0.f, 0.f, 0.f};

  int nk = K / BK;
  for (int kt = 0; kt < nk; ++kt) {
    // ---- stage A (bf16 [M,K], 16B vector loads) ----
    constexpr int AV = TBM * BK / (256 * 8);
#pragma unroll
    for (int v = 0; v < AV; ++v) {
      int e = (t + v * 256) * 8;
      int r = e >> 5, c = e & 31;
      *(int4*)&As[r * LSTR + c] =
          *(const int4*)(Ab + (size_t)(m0 + r) * lda + (size_t)kt * BK + c);
    }
    // ---- stage B ----
    if constexpr (BT && BBF16) {  // bf16 [N,K]: direct rows (scores K-buf, PV vt)
      constexpr int BV = TBN * BK / (256 * 8);
#pragma unroll
      for (int v = 0; v < BV; ++v) {
        int e = (t + v * 256) * 8;
        int r = e >> 5, c = e & 31;
        int4 val = {0, 0, 0, 0};
        if (n0 + r < N)
          val = *(const int4*)(Bb16 + (size_t)(n0 + r) * ldb +
                               (size_t)kt * BK + c);
        *(int4*)&Bs[r * LSTR + c] = val;
      }
    } else if constexpr (BT && !BBF16) {  // f32 [N,K]: tok_emb for logits
      constexpr int BV = TBN * BK / (256 * 8);
#pragma unroll
      for (int v = 0; v < BV; ++v) {
        int e = (t + v * 256) * 8;
        int r = e >> 5, c = e & 31;
        union { u16 us[8]; int4 i4; } tmp;
        tmp.i4 = make_int4(0, 0, 0, 0);
        if (n0 + r < N) {
          const float* s0 = Bbf + (size_t)(n0 + r) * ldb + (size_t)kt * BK + c;
          float4 f0 = *(const float4*)s0;
          float4 f1 = *(const float4*)(s0 + 4);
          tmp.us[0] = f2b(f0.x); tmp.us[1] = f2b(f0.y);
          tmp.us[2] = f2b(f0.z); tmp.us[3] = f2b(f0.w);
          tmp.us[4] = f2b(f1.x); tmp.us[5] = f2b(f1.y);
          tmp.us[6] = f2b(f1.z); tmp.us[7] = f2b(f1.w);
        }
        *(int4*)&Bs[r * LSTR + c] = tmp.i4;
      }
    } else {  // f32 weights [K,N]: coalesced float4 reads, transposed LDS writes
      constexpr int LN_ = TBN / 4;
      constexpr int KS = 256 / LN_;
      int tk = t / LN_;
      int tn = (t % LN_) * 4;
#pragma unroll
      for (int it = 0; it < BK / KS; ++it) {
        int k = it * KS + tk;
        float4 w2 =
            *(const float4*)(Bbf + (size_t)(kt * BK + k) * ldb + n0 + tn);
        Bs[(tn + 0) * LSTR + k] = f2b(w2.x);
        Bs[(tn + 1) * LSTR + k] = f2b(w2.y);
        Bs[(tn + 2) * LSTR + k] = f2b(w2.z);
        Bs[(tn + 3) * LSTR + k] = f2b(w2.w);
      }
    }
    __syncthreads();

    bf16x8 af[FM], bfr[FN];
#pragma unroll
    for (int i = 0; i < FM; ++i)
      af[i] = *(const bf16x8*)&As[(wm * (TBM / 2) + i * 16 + lr) * LSTR + lk];
#pragma unroll
    for (int j = 0; j < FN; ++j)
      bfr[j] = *(const bf16x8*)&Bs[(wn * (TBN / 2) + j * 16 + lr) * LSTR + lk];
#pragma unroll
    for (int i = 0; i < FM; ++i)
#pragma unroll
      for (int j = 0; j < FN; ++j)
        acc[i][j] = __builtin_amdgcn_mfma_f32_16x16x32_bf16(af[i], bfr[j],
                                                            acc[i][j], 0, 0, 0);
    __syncthreads();
  }

  // ---- epilogue (C/D frag: col = lane&15, row = (lane>>4)*4 + r) ----
  int rb = (lane >> 4) * 4;
#pragma unroll
  for (int i = 0; i < FM; ++i) {
#pragma unroll
    for (int j = 0; j < FN; ++j) {
      int m = m0 + wm * (TBM / 2) + i * 16 + rb;
      int n = n0 + wn * (TBN / 2) + j * 16 + lr;
      f32x4 a = acc[i][j];
      if constexpr (MODE == 0 || MODE == 5) {
        if (n < N) {
          u16* C = (u16*)Cp + coff;
#pragma unroll
          for (int r = 0; r < 4; ++r) C[(size_t)(m + r) * ldc + n] = f2b(a[r]);
        }
      } else if constexpr (MODE == 1) {
        float* C = (float*)Cp;
        float bv = bias[n];
#pragma unroll
        for (int r = 0; r < 4; ++r) {
          size_t ix = (size_t)(m + r) * ldc + n;
          C[ix] += a[r] + bv;
        }
      } else if constexpr (MODE == 2) {
        u16* C = (u16*)Cp;
        float bv = bias[n];
#pragma unroll
        for (int r = 0; r < 4; ++r) {
          float u2 = a[r] + bv;
          float g = 0.5f * u2 *
                    (1.f + tanhf(0.7978845608f * (u2 + 0.044715f * u2 * u2 * u2)));
          C[(size_t)(m + r) * ldc + n] = f2b(g);
        }
      } else if constexpr (MODE == 4) {
        float* C = (float*)Cp + coff;
#pragma unroll
        for (int r = 0; r < 4; ++r) C[(size_t)(m + r) * ldc + n] = a[r];
      } else if constexpr (MODE == 6) {
        if (n < N) {
          float* C = (float*)Cp;
#pragma unroll
          for (int r = 0; r < 4; ++r) C[(size_t)(m + r) * ldc + n] = a[r];
        }
      } else if constexpr (MODE == 7) {
        if (sel < 2) {  // Q or K: plain bf16 [M,D]
          u16* C = sel == 0 ? (u16*)Cp : (u16*)Cp2;
#pragma unroll
          for (int r = 0; r < 4; ++r) C[(size_t)(m + r) * ldc + n] = f2b(a[r]);
        } else {  // V: write transposed vt[b][d][s] so PV's B is contig-K
          u16* C = (u16*)Cp3;
          int bb = m >> 9, s2 = m & (SQ - 1);
          ushort4 w4;
          w4.x = f2b(a[0]); w4.y = f2b(a[1]);
          w4.z = f2b(a[2]); w4.w = f2b(a[3]);
          *(ushort4*)&C[((size_t)bb * DM + n) * SQ + s2] = w4;
        }
      }
    }
  }
}

__global__ __launch_bounds__(256) void embed_k(const int* __restrict__ idx,
                                               const float* __restrict__ tok,
                                               const float* __restrict__ pos,
                                               float* __restrict__ x) {
  int row = blockIdx.x, t = threadIdx.x;
  int s = row & (SQ - 1);
  int id = idx[row];
  float4 a = *(const float4*)(tok + (size_t)id * DM + t * 4);
  float4 p = *(const float4*)(pos + (size_t)s * DM + t * 4);
  a.x += p.x; a.y += p.y; a.z += p.z; a.w += p.w;
  *(float4*)(x + (size_t)row * DM + t * 4) = a;
}

__global__ __launch_bounds__(256) void ln_k(const float* __restrict__ x,
                                            const float* __restrict__ sc,
                                            const float* __restrict__ sh,
                                            u16* __restrict__ o) {
  int row = blockIdx.x, t = threadIdx.x;
  const float* xr = x + (size_t)row * DM;
  float4 v = *(const float4*)(xr + t * 4);
  float s = v.x + v.y + v.z + v.w;
#pragma unroll
  for (int d = 32; d; d >>= 1) s += __shfl_xor(s, d);
  __shared__ float red[8];
  if ((t & 63) == 0) red[t >> 6] = s;
  __syncthreads();
  float mean = (red[0] + red[1] + red[2] + red[3]) * (1.f / DM);
  float dx = v.x - mean, dy = v.y - mean, dz = v.z - mean, dw = v.w - mean;
  float s2 = dx * dx + dy * dy + dz * dz + dw * dw;
#pragma unroll
  for (int d = 32; d; d >>= 1) s2 += __shfl_xor(s2, d);
  if ((t & 63) == 0) red[4 + (t >> 6)] = s2;
  __syncthreads();
  float var = (red[4] + red[5] + red[6] + red[7]) * (1.f / DM);
  float rstd = 1.f / sqrtf(var + 1e-6f);
  float4 g = *(const float4*)(sc + t * 4);
  float4 b = *(const float4*)(sh + t * 4);
  ushort4 w4;
  w4.x = f2b(g.x * (dx * rstd) + b.x);
  w4.y = f2b(g.y * (dy * rstd) + b.y);
  w4.z = f2b(g.z * (dz * rstd) + b.z);
  w4.w = f2b(g.w * (dw * rstd) + b.w);
  *(ushort4*)(o + (size_t)row * DM + t * 4) = w4;
}

// one block per (b,h,i) row: causal mask + scale + softmax, f32 -> bf16 P
__global__ __launch_bounds__(256) void softmax_k(const float* __restrict__ scr,
                                                 u16* __restrict__ p) {
  int z = blockIdx.x;
  int i = z & (SQ - 1);
  const float* row = scr + (size_t)z * SQ;
  u16* pr = p + (size_t)z * SQ;
  int t = threadIdx.x;
  int j0 = t, j1 = t + 256;
  float v0 = (j0 <= i) ? row[j0] * 0.125f : -1e30f;
  float v1 = (j1 <= i) ? row[j1] * 0.125f : -1e30f;
  float mx = fmaxf(v0, v1);
#pragma unroll
  for (int d = 32; d; d >>= 1) mx = fmaxf(mx, __shfl_xor(mx, d));
  __shared__ float red[8];
  if ((t & 63) == 0) red[t >> 6] = mx;
  __syncthreads();
  mx = fmaxf(fmaxf(red[0], red[1]), fmaxf(red[2], red[3]));
  float e0 = (j0 <= i) ? __expf(v0 - mx) : 0.f;
  float e1 = (j1 <= i) ? __expf(v1 - mx) : 0.f;
  float s = e0 + e1;
#pragma unroll
  for (int d = 32; d; d >>= 1) s += __shfl_xor(s, d);
  if ((t & 63) == 0) red[4 + (t >> 6)] = s;
  __syncthreads();
  s = red[4] + red[5] + red[6] + red[7];
  float inv = 1.f / s;
  pr[j0] = f2b(e0 * inv);
  pr[j1] = f2b(e1 * inv);
}

extern "C" void kernel_launch(void* const* d_in, const int* in_sizes, int n_in,
                              void* d_out, int out_size, void* d_ws,
                              size_t ws_size, hipStream_t stream) {
  const int* idx = (const int*)d_in[0];
  const float* tok = (const float*)d_in[1];
  const float* pos = (const float*)d_in[2];
  const float* Wq = (const float*)d_in[3];
  const float* Wk = (const float*)d_in[4];
  const float* Wv = (const float*)d_in[5];
  const float* Wo = (const float*)d_in[6];
  const float* bo = (const float*)d_in[7];
  const float* W1 = (const float*)d_in[8];
  const float* b1 = (const float*)d_in[9];
  const float* W2 = (const float*)d_in[10];
  const float* b2 = (const float*)d_in[11];
  const float* ln1s = (const float*)d_in[12];
  const float* ln1b = (const float*)d_in[13];
  const float* ln2s = (const float*)d_in[14];
  const float* ln2b = (const float*)d_in[15];
  const float* lnfs = (const float*)d_in[16];
  const float* lnfb = (const float*)d_in[17];
  float* out = (float*)d_out;

  // workspace carve (~145 MB)
  char* w = (char*)d_ws;
  float* x = (float*)w;  w += (size_t)MR * DM * 4;           // residual f32
  u16* h = (u16*)w;      w += (size_t)MR * DM * 2;           // LN out bf16
  u16* qb = (u16*)w;     w += (size_t)MR * DM * 2;
  u16* kb = (u16*)w;     w += (size_t)MR * DM * 2;
  u16* vt = (u16*)w;     w += (size_t)NB * DM * SQ * 2;      // V transposed
  u16* cx = (u16*)w;     w += (size_t)MR * DM * 2;           // attn ctx
  u16* ff = (u16*)w;     w += (size_t)MR * DF * 2;           // gelu out
  u16* pb = (u16*)w;     w += (size_t)NB * NH * SQ * SQ * 2; // softmax P
  float* sc = (float*)w;                                      // scores f32 64MB

  dim3 T(256);
  embed_k<<<MR, T, 0, stream>>>(idx, tok, pos, x);
  for (int l = 0; l < LL; ++l) {
    size_t wo_ = (size_t)l * DM * DM;
    ln_k<<<MR, T, 0, stream>>>(x, ln1s + l * DM, ln1b + l * DM, h);
    gemm_k<7, false, false, 64, 128><<<dim3(32, 24), T, 0, stream>>>(
        h, Wq + wo_, Wk + wo_, Wv + wo_, qb, kb, vt, nullptr, MR, DM, DM, DM,
        DM, DM);
    gemm_k<4, true, true, 128, 128><<<dim3(4, 4, NB * NH), T, 0, stream>>>(
        qb, kb, nullptr, nullptr, sc, nullptr, nullptr, nullptr, SQ, SQ, DHD,
        DM, DM, SQ);
    softmax_k<<<NB * NH * SQ, T, 0, stream>>>(sc, pb);
    gemm_k<5, true, true, 128, 128><<<dim3(4, 1, NB * NH), T, 0, stream>>>(
        pb, vt, nullptr, nullptr, cx, nullptr, nullptr, nullptr, SQ, DHD, SQ,
        SQ, SQ, DM);
    gemm_k<1, false, false, 64, 128><<<dim3(32, 8), T, 0, stream>>>(
        cx, Wo + wo_, nullptr, nullptr, x, nullptr, nullptr, bo + l * DM, MR,
        DM, DM, DM, DM, DM);
    ln_k<<<MR, T, 0, stream>>>(x, ln2s + l * DM, ln2b + l * DM, h);
    gemm_k<2, false, false, 128, 128><<<dim3(16, 32), T, 0, stream>>>(
        h, W1 + (size_t)l * DM * DF, nullptr, nullptr, ff, nullptr, nullptr,
        b1 + l * DF, MR, DF, DM, DM, DF, DF);
    gemm_k<1, false, false, 64, 128><<<dim3(32, 8), T, 0, stream>>>(
        ff, W2 + (size_t)l * DF * DM, nullptr, nullptr, x, nullptr, nullptr,
        b2 + l * DM, MR, DM, DF, DF, DM, DM);
  }
  ln_k<<<MR, T, 0, stream>>>(x, lnfs, lnfb, h);
  gemm_k<6, true, false, 128, 128>
      <<<dim3(16, (NV + 127) / 128), T, 0, stream>>>(
          h, tok, nullptr, nullptr, out, nullptr, nullptr, nullptr, MR, NV, DM,
          DM, DM, NV);
}

// Round 2
// 3353.958 us; speedup vs baseline: 2.1646x; 2.1646x over previous
//
#include <hip/hip_runtime.h>

// GPT-2 forward. Round 2: pre-convert weights to bf16 [N,K] once per forward,
// m97-structure GEMM (global_load_lds w=16, linear LDS, 2-barrier K-loop).

#define LL 12
#define DM 1024
#define NH 16
#define DHD 64
#define NV 50257
#define NVP 50304  // 393*128, padded vocab for tile-exact logits GEMM
#define SQ 512
#define NB 4
#define DF 4096
#define MR (NB * SQ)
#define BK 32

typedef short bf16x8 __attribute__((ext_vector_type(8)));
typedef float f32x4 __attribute__((ext_vector_type(4)));
typedef unsigned short u16;

__device__ __forceinline__ u16 f2b(float f) {  // f32 -> bf16 RNE
  unsigned u = __float_as_uint(f);
  u += 0x7fff + ((u >> 16) & 1);
  return (u16)(u >> 16);
}

__device__ __forceinline__ void gload16(const u16* g, u16* l) {
  __builtin_amdgcn_global_load_lds(
      (const __attribute__((address_space(1))) unsigned*)g,
      (__attribute__((address_space(3))) unsigned*)l, 16, 0, 0);
}

// ---------------- GEMM: C[M,N] = A[M,K](bf16) @ B[N,K](bf16)^T ----------------
// MODE 1: Cf32 += acc + bias (Wo, W2)     MODE 2: bf16 C = gelu(acc+bias) (W1)
// MODE 4: scores f32, z=(b,h), causal early-exit
// MODE 5: PV -> bf16 ctx slice            MODE 6: logits f32, n<NV guard
// MODE 7: QKV fused, route by n>>10, V transposed
template <int MODE, int TBM, int TBN>
__global__ __launch_bounds__(256) void gemm_k(
    const u16* __restrict__ A, const u16* __restrict__ B, void* __restrict__ Cp,
    void* __restrict__ Cp2, void* __restrict__ Cp3,
    const float* __restrict__ bias, int N, int K, int lda, int ldb, int ldc) {
  int mt = blockIdx.x, nt = blockIdx.y, z = blockIdx.z;
  int m0 = mt * TBM, n0 = nt * TBN;
  const u16* Ab = A;
  const u16* Bb = B;
  size_t coff = 0;
  if constexpr (MODE == 4) {
    if (n0 > m0) return;  // fully-masked tile
    int b = z >> 4, h = z & 15;
    Ab = A + (size_t)b * SQ * DM + h * DHD;
    Bb = B + (size_t)b * SQ * DM + h * DHD;
    coff = (size_t)z * SQ * SQ;
  }
  if constexpr (MODE == 5) {
    int b = z >> 4, h = z & 15;
    Ab = A + (size_t)z * SQ * SQ;
    Bb = B + ((size_t)b * DM + h * DHD) * SQ;
    coff = (size_t)b * SQ * DM + h * DHD;
  }

  __shared__ u16 As[TBM * BK];
  __shared__ u16 Bs[TBN * BK];

  int t = threadIdx.x, lane = t & 63, wave = t >> 6;
  int wm = wave >> 1, wn = wave & 1;
  int lr = lane & 15, lk = (lane >> 4) * 8;
  int srow = lane >> 2, scol = (lane & 3) * 8;  // staging: 4 lanes/row, 16B each
  constexpr int FM = TBM / 32, FN = TBN / 32;

  f32x4 acc[FM][FN];
#pragma unroll
  for (int i = 0; i < FM; ++i)
#pragma unroll
    for (int j = 0; j < FN; ++j) acc[i][j] = (f32x4){0.f, 0.f, 0.f, 0.f};

  int nk = K / BK;
  for (int kt = 0; kt < nk; ++kt) {
    constexpr int ACH = TBM / 16;  // 1KB chunks (16 rows x 32 cols bf16)
#pragma unroll
    for (int cc = 0; cc < ACH / 4; ++cc) {
      int c = cc * 4 + wave;
      gload16(Ab + (size_t)(m0 + c * 16 + srow) * lda + kt * BK + scol,
              &As[c * 512]);
    }
    constexpr int BCH = TBN / 16;
#pragma unroll
    for (int cc = 0; cc < BCH / 4; ++cc) {
      int c = cc * 4 + wave;
      gload16(Bb + (size_t)(n0 + c * 16 + srow) * ldb + kt * BK + scol,
              &Bs[c * 512]);
    }
    __syncthreads();

    bf16x8 af[FM], bq[FN];
#pragma unroll
    for (int i = 0; i < FM; ++i)
      af[i] = *(const bf16x8*)&As[(wm * (TBM / 2) + i * 16 + lr) * BK + lk];
#pragma unroll
    for (int j = 0; j < FN; ++j)
      bq[j] = *(const bf16x8*)&Bs[(wn * (TBN / 2) + j * 16 + lr) * BK + lk];
#pragma unroll
    for (int i = 0; i < FM; ++i)
#pragma unroll
      for (int j = 0; j < FN; ++j)
        acc[i][j] = __builtin_amdgcn_mfma_f32_16x16x32_bf16(af[i], bq[j],
                                                            acc[i][j], 0, 0, 0);
    __syncthreads();
  }

  // epilogue (C/D frag: col = lane&15, row = (lane>>4)*4 + r)
  int rb = (lane >> 4) * 4;
#pragma unroll
  for (int i = 0; i < FM; ++i) {
#pragma unroll
    for (int j = 0; j < FN; ++j) {
      int m = m0 + wm * (TBM / 2) + i * 16 + rb;
      int n = n0 + wn * (TBN / 2) + j * 16 + lr;
      f32x4 a = acc[i][j];
      if constexpr (MODE == 1) {
        float* C = (float*)Cp;
        float bv = bias[n];
#pragma unroll
        for (int r = 0; r < 4; ++r) {
          size_t ix = (size_t)(m + r) * ldc + n;
          C[ix] += a[r] + bv;
        }
      } else if constexpr (MODE == 2) {
        u16* C = (u16*)Cp;
        float bv = bias[n];
#pragma unroll
        for (int r = 0; r < 4; ++r) {
          float u2 = a[r] + bv;
          float g =
              0.5f * u2 *
              (1.f + tanhf(0.7978845608f * (u2 + 0.044715f * u2 * u2 * u2)));
          C[(size_t)(m + r) * ldc + n] = f2b(g);
        }
      } else if constexpr (MODE == 4) {
        float* C = (float*)Cp + coff;
#pragma unroll
        for (int r = 0; r < 4; ++r) C[(size_t)(m + r) * ldc + n] = a[r];
      } else if constexpr (MODE == 5) {
        u16* C = (u16*)Cp + coff;
#pragma unroll
        for (int r = 0; r < 4; ++r) C[(size_t)(m + r) * ldc + n] = f2b(a[r]);
      } else if constexpr (MODE == 6) {
        if (n < NV) {
          float* C = (float*)Cp;
#pragma unroll
          for (int r = 0; r < 4; ++r) C[(size_t)(m + r) * ldc + n] = a[r];
        }
      } else if constexpr (MODE == 7) {
        int sel = n >> 10, nn = n & 1023;
        if (sel < 2) {
          u16* C = sel == 0 ? (u16*)Cp : (u16*)Cp2;
#pragma unroll
          for (int r = 0; r < 4; ++r) C[(size_t)(m + r) * ldc + nn] = f2b(a[r]);
        } else {  // V: vt[b][d][s], contig-K rows for PV
          u16* C = (u16*)Cp3;
          int bb = m >> 9, s2 = m & (SQ - 1);
          ushort4 w4;
          w4.x = f2b(a[0]); w4.y = f2b(a[1]);
          w4.z = f2b(a[2]); w4.w = f2b(a[3]);
          *(ushort4*)&C[((size_t)bb * DM + nn) * SQ + s2] = w4;
        }
      }
    }
  }
}

// f32 [K,N] -> bf16 [N,K] tiled transpose; z selects among 4 sources
__global__ __launch_bounds__(256) void transp_k(
    const float* __restrict__ S0, const float* __restrict__ S1,
    const float* __restrict__ S2, const float* __restrict__ S3,
    u16* __restrict__ dst, int K, int N, int dzstride) {
  int z = blockIdx.z;
  const float* src = z == 0 ? S0 : z == 1 ? S1 : z == 2 ? S2 : S3;
  u16* d = dst + (size_t)z * dzstride;
  int n0 = blockIdx.x * 64, k0 = blockIdx.y * 64;
  __shared__ u16 tl[64][72];
  int t = threadIdx.x;
  int tn = (t & 15) * 4, tk = t >> 4;
#pragma unroll
  for (int it = 0; it < 4; ++it) {
    int k = tk + it * 16;
    float4 v = *(const float4*)(src + (size_t)(k0 + k) * N + n0 + tn);
    tl[tn + 0][k] = f2b(v.x);
    tl[tn + 1][k] = f2b(v.y);
    tl[tn + 2][k] = f2b(v.z);
    tl[tn + 3][k] = f2b(v.w);
  }
  __syncthreads();
  int wn = t >> 3, wk = (t & 7) * 8;
#pragma unroll
  for (int it = 0; it < 2; ++it) {
    int n = wn + it * 32;
    int4 v = *(const int4*)&tl[n][wk];
    *(int4*)(d + (size_t)(n0 + n) * K + k0 + wk) = v;
  }
}

// tok_emb f32 [V,D] -> bf16 [NVP,D], zero pad rows
__global__ __launch_bounds__(256) void convtok_k(const float* __restrict__ tok,
                                                 u16* __restrict__ dst) {
  size_t r = blockIdx.x;
  int t = threadIdx.x;
  ushort4 w = {0, 0, 0, 0};
  if (r < NV) {
    float4 v = *(const float4*)(tok + r * DM + t * 4);
    w.x = f2b(v.x); w.y = f2b(v.y); w.z = f2b(v.z); w.w = f2b(v.w);
  }
  *(ushort4*)(dst + r * DM + t * 4) = w;
}

__global__ __launch_bounds__(256) void embed_k(const int* __restrict__ idx,
                                               const float* __restrict__ tok,
                                               const float* __restrict__ pos,
                                               float* __restrict__ x) {
  int row = blockIdx.x, t = threadIdx.x;
  int s = row & (SQ - 1);
  int id = idx[row];
  float4 a = *(const float4*)(tok + (size_t)id * DM + t * 4);
  float4 p = *(const float4*)(pos + (size_t)s * DM + t * 4);
  a.x += p.x; a.y += p.y; a.z += p.z; a.w += p.w;
  *(float4*)(x + (size_t)row * DM + t * 4) = a;
}

__global__ __launch_bounds__(256) void ln_k(const float* __restrict__ x,
                                            const float* __restrict__ sc,
                                            const float* __restrict__ sh,
                                            u16* __restrict__ o) {
  int row = blockIdx.x, t = threadIdx.x;
  const float* xr = x + (size_t)row * DM;
  float4 v = *(const float4*)(xr + t * 4);
  float s = v.x + v.y + v.z + v.w;
#pragma unroll
  for (int d = 32; d; d >>= 1) s += __shfl_xor(s, d);
  __shared__ float red[8];
  if ((t & 63) == 0) red[t >> 6] = s;
  __syncthreads();
  float mean = (red[0] + red[1] + red[2] + red[3]) * (1.f / DM);
  float dx = v.x - mean, dy = v.y - mean, dz = v.z - mean, dw = v.w - mean;
  float s2 = dx * dx + dy * dy + dz * dz + dw * dw;
#pragma unroll
  for (int d = 32; d; d >>= 1) s2 += __shfl_xor(s2, d);
  if ((t & 63) == 0) red[4 + (t >> 6)] = s2;
  __syncthreads();
  float var = (red[4] + red[5] + red[6] + red[7]) * (1.f / DM);
  float rstd = 1.f / sqrtf(var + 1e-6f);
  float4 g = *(const float4*)(sc + t * 4);
  float4 b = *(const float4*)(sh + t * 4);
  ushort4 w4;
  w4.x = f2b(g.x * (dx * rstd) + b.x);
  w4.y = f2b(g.y * (dy * rstd) + b.y);
  w4.z = f2b(g.z * (dz * rstd) + b.z);
  w4.w = f2b(g.w * (dw * rstd) + b.w);
  *(ushort4*)(o + (size_t)row * DM + t * 4) = w4;
}

// one block per (b,h,i) row: causal mask + scale + softmax, f32 -> bf16 P
__global__ __launch_bounds__(256) void softmax_k(const float* __restrict__ scr,
                                                 u16* __restrict__ p) {
  int z = blockIdx.x;
  int i = z & (SQ - 1);
  const float* row = scr + (size_t)z * SQ;
  u16* pr = p + (size_t)z * SQ;
  int t = threadIdx.x;
  int j0 = t, j1 = t + 256;
  float v0 = (j0 <= i) ? row[j0] * 0.125f : -1e30f;
  float v1 = (j1 <= i) ? row[j1] * 0.125f : -1e30f;
  float mx = fmaxf(v0, v1);
#pragma unroll
  for (int d = 32; d; d >>= 1) mx = fmaxf(mx, __shfl_xor(mx, d));
  __shared__ float red[8];
  if ((t & 63) == 0) red[t >> 6] = mx;
  __syncthreads();
  mx = fmaxf(fmaxf(red[0], red[1]), fmaxf(red[2], red[3]));
  float e0 = (j0 <= i) ? __expf(v0 - mx) : 0.f;
  float e1 = (j1 <= i) ? __expf(v1 - mx) : 0.f;
  float s = e0 + e1;
#pragma unroll
  for (int d = 32; d; d >>= 1) s += __shfl_xor(s, d);
  if ((t & 63) == 0) red[4 + (t >> 6)] = s;
  __syncthreads();
  s = red[4] + red[5] + red[6] + red[7];
  float inv = 1.f / s;
  pr[j0] = f2b(e0 * inv);
  pr[j1] = f2b(e1 * inv);
}

extern "C" void kernel_launch(void* const* d_in, const int* in_sizes, int n_in,
                              void* d_out, int out_size, void* d_ws,
                              size_t ws_size, hipStream_t stream) {
  const int* idx = (const int*)d_in[0];
  const float* tok = (const float*)d_in[1];
  const float* pos = (const float*)d_in[2];
  const float* Wq = (const float*)d_in[3];
  const float* Wk = (const float*)d_in[4];
  const float* Wv = (const float*)d_in[5];
  const float* Wo = (const float*)d_in[6];
  const float* bo = (const float*)d_in[7];
  const float* W1 = (const float*)d_in[8];
  const float* b1 = (const float*)d_in[9];
  const float* W2 = (const float*)d_in[10];
  const float* b2 = (const float*)d_in[11];
  const float* ln1s = (const float*)d_in[12];
  const float* ln1b = (const float*)d_in[13];
  const float* ln2s = (const float*)d_in[14];
  const float* ln2b = (const float*)d_in[15];
  const float* lnfs = (const float*)d_in[16];
  const float* lnfb = (const float*)d_in[17];
  float* out = (float*)d_out;

  // workspace carve (~164 MB); tokT aliases dead ff/pb/sc at the end
  char* w = (char*)d_ws;
  float* x = (float*)w;  w += (size_t)MR * DM * 4;            // 8 MB
  u16* h = (u16*)w;      w += (size_t)MR * DM * 2;            // 4
  u16* qb = (u16*)w;     w += (size_t)MR * DM * 2;            // 4
  u16* kb = (u16*)w;     w += (size_t)MR * DM * 2;            // 4
  u16* vt = (u16*)w;     w += (size_t)NB * DM * SQ * 2;       // 4
  u16* cx = (u16*)w;     w += (size_t)MR * DM * 2;            // 4
  u16* ff = (u16*)w;     w += (size_t)MR * DF * 2;            // 16
  u16* pb = (u16*)w;     w += (size_t)NB * NH * SQ * SQ * 2;  // 32
  float* sc = (float*)w; w += (size_t)NB * NH * SQ * SQ * 4;  // 64
  u16* wb = (u16*)w;     // 24 MB: QKVO (4M elems) + W1' (4M) + W2' (4M)
  u16* wqkv = wb;                    // [3072,1024] (+Wo' at +3M)
  u16* wo_b = wb + (size_t)3 * DM * DM;
  u16* wb1 = wb + (size_t)4 * DM * DM;   // [4096,1024]
  u16* wb2 = wb1 + (size_t)DM * DF;      // [1024,4096]
  u16* tokT = (u16*)ff;  // 98.3 MB over ff+pb+sc (112 MB)

  dim3 T(256);
  embed_k<<<MR, T, 0, stream>>>(idx, tok, pos, x);
  for (int l = 0; l < LL; ++l) {
    size_t wo_ = (size_t)l * DM * DM;
    size_t w1_ = (size_t)l * DM * DF;
    transp_k<<<dim3(16, 16, 4), T, 0, stream>>>(Wq + wo_, Wk + wo_, Wv + wo_,
                                                Wo + wo_, wb, DM, DM, DM * DM);
    transp_k<<<dim3(64, 16, 1), T, 0, stream>>>(W1 + w1_, nullptr, nullptr,
                                                nullptr, wb1, DM, DF, 0);
    transp_k<<<dim3(16, 64, 1), T, 0, stream>>>(W2 + w1_, nullptr, nullptr,
                                                nullptr, wb2, DF, DM, 0);
    ln_k<<<MR, T, 0, stream>>>(x, ln1s + l * DM, ln1b + l * DM, h);
    gemm_k<7, 128, 128><<<dim3(16, 24), T, 0, stream>>>(
        h, wqkv, qb, kb, vt, nullptr, 3 * DM, DM, DM, DM, DM);
    gemm_k<4, 128, 128><<<dim3(4, 4, NB * NH), T, 0, stream>>>(
        qb, kb, sc, nullptr, nullptr, nullptr, SQ, DHD, DM, DM, SQ);
    softmax_k<<<NB * NH * SQ, T, 0, stream>>>(sc, pb);
    gemm_k<5, 128, 64><<<dim3(4, 1, NB * NH), T, 0, stream>>>(
        pb, vt, cx, nullptr, nullptr, nullptr, DHD, SQ, SQ, SQ, DM);
    gemm_k<1, 64, 128><<<dim3(32, 8), T, 0, stream>>>(
        cx, wo_b, x, nullptr, nullptr, bo + l * DM, DM, DM, DM, DM, DM);
    ln_k<<<MR, T, 0, stream>>>(x, ln2s + l * DM, ln2b + l * DM, h);
    gemm_k<2, 128, 128><<<dim3(16, 32), T, 0, stream>>>(
        h, wb1, ff, nullptr, nullptr, b1 + l * DF, DF, DM, DM, DM, DF);
    gemm_k<1, 64, 128><<<dim3(32, 8), T, 0, stream>>>(
        ff, wb2, x, nullptr, nullptr, b2 + l * DM, DM, DF, DF, DF, DM);
  }
  ln_k<<<MR, T, 0, stream>>>(x, lnfs, lnfb, h);
  convtok_k<<<NVP, T, 0, stream>>>(tok, tokT);
  gemm_k<6, 128, 128><<<dim3(16, NVP / 128), T, 0, stream>>>(
      h, tokT, out, nullptr, nullptr, nullptr, NV, DM, DM, DM, NV);
}

// Round 3
// 2910.273 us; speedup vs baseline: 2.4946x; 1.1525x over previous
//
#include <hip/hip_runtime.h>

// GPT-2 forward. Round 3: flash attention (fused scores/softmax/PV),
// XCD-chunked swizzle on all GEMMs, merged weight-transpose launch.

#define LL 12
#define DM 1024
#define NH 16
#define DHD 64
#define NV 50257
#define NVP 50304
#define SQ 512
#define NB 4
#define DF 4096
#define MR (NB * SQ)
#define BK 32

typedef short bf16x8 __attribute__((ext_vector_type(8)));
typedef float f32x4 __attribute__((ext_vector_type(4)));
typedef unsigned short u16;

__device__ __forceinline__ u16 f2b(float f) {  // f32 -> bf16 RNE
  unsigned u = __float_as_uint(f);
  u += 0x7fff + ((u >> 16) & 1);
  return (u16)(u >> 16);
}

__device__ __forceinline__ void gload16(const u16* g, u16* l) {
  __builtin_amdgcn_global_load_lds(
      (const __attribute__((address_space(1))) unsigned*)g,
      (__attribute__((address_space(3))) unsigned*)l, 16, 0, 0);
}

// ---------------- GEMM: C[M,N] = A[M,K](bf16) @ B[N,K](bf16)^T --------------
// MODE 1: Cf32 += acc + bias   MODE 2: bf16 C = gelu(acc+bias)
// MODE 6: logits f32, n<NV     MODE 7: QKV fused (route n>>10), V transposed
// 1D grid, XCD-chunked swizzle (requires gridDim.x % 8 == 0), mt = 2^MTLOG.
template <int MODE, int TBM, int TBN, int MTLOG>
__global__ __launch_bounds__(256) void gemm_k(
    const u16* __restrict__ A, const u16* __restrict__ B, void* __restrict__ Cp,
    void* __restrict__ Cp2, void* __restrict__ Cp3,
    const float* __restrict__ bias, int N, int K, int lda, int ldb, int ldc) {
  int id = blockIdx.x;
  int q8 = gridDim.x >> 3;
  int swz = (id & 7) * q8 + (id >> 3);
  int mt = swz & ((1 << MTLOG) - 1), nt = swz >> MTLOG;
  int m0 = mt * TBM, n0 = nt * TBN;

  __shared__ u16 As[TBM * BK];
  __shared__ u16 Bs[TBN * BK];

  int t = threadIdx.x, lane = t & 63, wave = t >> 6;
  int wm = wave >> 1, wn = wave & 1;
  int lr = lane & 15, lk = (lane >> 4) * 8;
  int srow = lane >> 2, scol = (lane & 3) * 8;
  constexpr int FM = TBM / 32, FN = TBN / 32;

  f32x4 acc[FM][FN];
#pragma unroll
  for (int i = 0; i < FM; ++i)
#pragma unroll
    for (int j = 0; j < FN; ++j) acc[i][j] = (f32x4){0.f, 0.f, 0.f, 0.f};

  int nk = K / BK;
  for (int kt = 0; kt < nk; ++kt) {
    constexpr int ACH = TBM / 16;
#pragma unroll
    for (int cc = 0; cc < ACH / 4; ++cc) {
      int c = cc * 4 + wave;
      gload16(A + (size_t)(m0 + c * 16 + srow) * lda + kt * BK + scol,
              &As[c * 512]);
    }
    constexpr int BCH = TBN / 16;
#pragma unroll
    for (int cc = 0; cc < BCH / 4; ++cc) {
      int c = cc * 4 + wave;
      gload16(B + (size_t)(n0 + c * 16 + srow) * ldb + kt * BK + scol,
              &Bs[c * 512]);
    }
    __syncthreads();

    bf16x8 af[FM], bq[FN];
#pragma unroll
    for (int i = 0; i < FM; ++i)
      af[i] = *(const bf16x8*)&As[(wm * (TBM / 2) + i * 16 + lr) * BK + lk];
#pragma unroll
    for (int j = 0; j < FN; ++j)
      bq[j] = *(const bf16x8*)&Bs[(wn * (TBN / 2) + j * 16 + lr) * BK + lk];
#pragma unroll
    for (int i = 0; i < FM; ++i)
#pragma unroll
      for (int j = 0; j < FN; ++j)
        acc[i][j] = __builtin_amdgcn_mfma_f32_16x16x32_bf16(af[i], bq[j],
                                                            acc[i][j], 0, 0, 0);
    __syncthreads();
  }

  int rb = (lane >> 4) * 4;
#pragma unroll
  for (int i = 0; i < FM; ++i) {
#pragma unroll
    for (int j = 0; j < FN; ++j) {
      int m = m0 + wm * (TBM / 2) + i * 16 + rb;
      int n = n0 + wn * (TBN / 2) + j * 16 + lr;
      f32x4 a = acc[i][j];
      if constexpr (MODE == 1) {
        float* C = (float*)Cp;
        float bv = bias[n];
#pragma unroll
        for (int r = 0; r < 4; ++r) {
          size_t ix = (size_t)(m + r) * ldc + n;
          C[ix] += a[r] + bv;
        }
      } else if constexpr (MODE == 2) {
        u16* C = (u16*)Cp;
        float bv = bias[n];
#pragma unroll
        for (int r = 0; r < 4; ++r) {
          float u2 = a[r] + bv;
          float g =
              0.5f * u2 *
              (1.f + tanhf(0.7978845608f * (u2 + 0.044715f * u2 * u2 * u2)));
          C[(size_t)(m + r) * ldc + n] = f2b(g);
        }
      } else if constexpr (MODE == 6) {
        if (n < NV) {
          float* C = (float*)Cp;
#pragma unroll
          for (int r = 0; r < 4; ++r) C[(size_t)(m + r) * ldc + n] = a[r];
        }
      } else if constexpr (MODE == 7) {
        int sel = n >> 10, nn = n & 1023;
        if (sel < 2) {
          u16* C = sel == 0 ? (u16*)Cp : (u16*)Cp2;
#pragma unroll
          for (int r = 0; r < 4; ++r) C[(size_t)(m + r) * ldc + nn] = f2b(a[r]);
        } else {  // V transposed: vt[b][d][s]
          u16* C = (u16*)Cp3;
          int bb = m >> 9, s2 = m & (SQ - 1);
          ushort4 w4;
          w4.x = f2b(a[0]); w4.y = f2b(a[1]);
          w4.z = f2b(a[2]); w4.w = f2b(a[3]);
          *(ushort4*)&C[((size_t)bb * DM + nn) * SQ + s2] = w4;
        }
      }
    }
  }
}

// -------- flash attention: one block = (qt 64 q-rows, b,h); 4 waves ---------
__global__ __launch_bounds__(256) void fattn_k(const u16* __restrict__ qb,
                                               const u16* __restrict__ kb,
                                               const u16* __restrict__ vt,
                                               u16* __restrict__ cx) {
  int id = blockIdx.x;
  int qt = id >> 6, bh = id & 63;  // bh-fastest: balances causal work per CU
  int b = bh >> 4, hh = bh & 15;
  int t = threadIdx.x, lane = t & 63, w = t >> 6;
  int lr = lane & 15, g = lane >> 4;

  __shared__ u16 Kt[64 * 72];        // [k=64][d=64] pad->72 (2-way banks)
  __shared__ u16 Vt[64 * 72];        // [d=64][k=64] (V^T)
  __shared__ u16 Pl[4 * 16 * 72];    // per-wave P [16 q][64 k]

  int qb0 = qt * 64;
  int qw = qb0 + w * 16;  // this wave's q rows

  bf16x8 aQ[2];  // Q A-frags: row=lr, k=g*8, two 32-wide d halves
#pragma unroll
  for (int f = 0; f < 2; ++f)
    aQ[f] = *(const bf16x8*)&qb[(size_t)(b * SQ + qw + lr) * DM + hh * DHD +
                                f * 32 + g * 8];

  f32x4 o[4];  // O[16 q][64 d] as 4 d-frags
#pragma unroll
  for (int j = 0; j < 4; ++j) o[j] = (f32x4){0.f, 0.f, 0.f, 0.f};
  f32x4 m4 = (f32x4){-3e38f, -3e38f, -3e38f, -3e38f};
  f32x4 l4 = (f32x4){0.f, 0.f, 0.f, 0.f};
  u16* Pw = &Pl[w * 16 * 72];

  for (int kt = 0; kt <= qt; ++kt) {
    int k0 = kt * 64;
    // stage K,V tiles (each 64 rows x 128B = 512 chunks of 16B; 256 thr x 2)
#pragma unroll
    for (int it = 0; it < 2; ++it) {
      int c = t + it * 256;
      int row = c >> 3, ch = c & 7;
      int4 kv = *(const int4*)&kb[(size_t)(b * SQ + k0 + row) * DM + hh * DHD +
                                  ch * 8];
      int4 vv = *(const int4*)&vt[(size_t)(b * DM + hh * DHD + row) * SQ + k0 +
                                  ch * 8];
      *(int4*)&Kt[row * 72 + ch * 8] = kv;
      *(int4*)&Vt[row * 72 + ch * 8] = vv;
    }
    __syncthreads();

    // S = Q @ K^T  (16 q x 64 k)
    f32x4 s[4];
#pragma unroll
    for (int j = 0; j < 4; ++j) s[j] = (f32x4){0.f, 0.f, 0.f, 0.f};
#pragma unroll
    for (int j = 0; j < 4; ++j)
#pragma unroll
      for (int f = 0; f < 2; ++f) {
        bf16x8 bk = *(const bf16x8*)&Kt[(j * 16 + lr) * 72 + f * 32 + g * 8];
        s[j] =
            __builtin_amdgcn_mfma_f32_16x16x32_bf16(aQ[f], bk, s[j], 0, 0, 0);
      }
    // scale + causal mask (diagonal tile only)
#pragma unroll
    for (int j = 0; j < 4; ++j) {
      int kcol = k0 + j * 16 + lr;
#pragma unroll
      for (int r = 0; r < 4; ++r) {
        float sv = s[j][r] * 0.125f;
        if (kt == qt && kcol > qw + g * 4 + r) sv = -1e30f;
        s[j][r] = sv;
      }
    }
    // row max over 64 k (4 frags + 16-lane butterfly)
    f32x4 fr;
#pragma unroll
    for (int r = 0; r < 4; ++r) {
      float v = fmaxf(fmaxf(s[0][r], s[1][r]), fmaxf(s[2][r], s[3][r]));
#pragma unroll
      for (int d = 1; d < 16; d <<= 1) v = fmaxf(v, __shfl_xor(v, d));
      float mn = fmaxf(m4[r], v);
      fr[r] = __expf(m4[r] - mn);
      m4[r] = mn;
    }
#pragma unroll
    for (int j = 0; j < 4; ++j)
#pragma unroll
      for (int r = 0; r < 4; ++r) o[j][r] *= fr[r];
    // P = exp(s - m); row sums; P -> LDS (bf16)
    f32x4 ps = (f32x4){0.f, 0.f, 0.f, 0.f};
#pragma unroll
    for (int j = 0; j < 4; ++j)
#pragma unroll
      for (int r = 0; r < 4; ++r) {
        float p = __expf(s[j][r] - m4[r]);
        s[j][r] = p;
        ps[r] += p;
      }
#pragma unroll
    for (int r = 0; r < 4; ++r) {
      float v = ps[r];
#pragma unroll
      for (int d = 1; d < 16; d <<= 1) v += __shfl_xor(v, d);
      l4[r] = l4[r] * fr[r] + v;
    }
#pragma unroll
    for (int j = 0; j < 4; ++j)
#pragma unroll
      for (int r = 0; r < 4; ++r)
        Pw[(g * 4 + r) * 72 + j * 16 + lr] = f2b(s[j][r]);
    // O += P @ V  (A = P from LDS, B = V^T rows)
#pragma unroll
    for (int f = 0; f < 2; ++f) {
      bf16x8 ap = *(const bf16x8*)&Pw[lr * 72 + f * 32 + g * 8];
#pragma unroll
      for (int j = 0; j < 4; ++j) {
        bf16x8 bv = *(const bf16x8*)&Vt[(j * 16 + lr) * 72 + f * 32 + g * 8];
        o[j] = __builtin_amdgcn_mfma_f32_16x16x32_bf16(ap, bv, o[j], 0, 0, 0);
      }
    }
    __syncthreads();
  }

#pragma unroll
  for (int r = 0; r < 4; ++r) {
    float inv = 1.f / l4[r];
#pragma unroll
    for (int j = 0; j < 4; ++j)
      cx[(size_t)(b * SQ + qw + g * 4 + r) * DM + hh * DHD + j * 16 + lr] =
          f2b(o[j][r] * inv);
  }
}

// -------- merged per-layer weight conversion: f32 [K,N] -> bf16 [N,K] -------
// 3072 tiles: [0,1024) QKVO (4x256), [1024,2048) W1, [2048,3072) W2
__global__ __launch_bounds__(256) void transpall_k(
    const float* __restrict__ Wq, const float* __restrict__ Wk,
    const float* __restrict__ Wv, const float* __restrict__ Wo,
    const float* __restrict__ W1, const float* __restrict__ W2,
    u16* __restrict__ wb) {
  int id = blockIdx.x;
  const float* src;
  u16* dst;
  int K, N, ktile, ntile;
  if (id < 1024) {
    int mat = id >> 8, rem = id & 255;
    ntile = rem & 15; ktile = rem >> 4;
    src = mat == 0 ? Wq : mat == 1 ? Wk : mat == 2 ? Wv : Wo;
    dst = wb + (size_t)mat * DM * DM;
    K = DM; N = DM;
  } else if (id < 2048) {
    int rem = id - 1024;
    ntile = rem & 63; ktile = rem >> 6;
    src = W1; dst = wb + (size_t)4 * DM * DM;
    K = DM; N = DF;
  } else {
    int rem = id - 2048;
    ntile = rem & 15; ktile = rem >> 4;
    src = W2; dst = wb + (size_t)4 * DM * DM + (size_t)DM * DF;
    K = DF; N = DM;
  }
  int n0 = ntile * 64, k0 = ktile * 64;
  __shared__ u16 tl[64][72];
  int t = threadIdx.x;
  int tn = (t & 15) * 4, tk = t >> 4;
#pragma unroll
  for (int it = 0; it < 4; ++it) {
    int k = tk + it * 16;
    float4 v = *(const float4*)(src + (size_t)(k0 + k) * N + n0 + tn);
    tl[tn + 0][k] = f2b(v.x);
    tl[tn + 1][k] = f2b(v.y);
    tl[tn + 2][k] = f2b(v.z);
    tl[tn + 3][k] = f2b(v.w);
  }
  __syncthreads();
  int wn = t >> 3, wk = (t & 7) * 8;
#pragma unroll
  for (int it = 0; it < 2; ++it) {
    int n = wn + it * 32;
    int4 v = *(const int4*)&tl[n][wk];
    *(int4*)(dst + (size_t)(n0 + n) * K + k0 + wk) = v;
  }
}

__global__ __launch_bounds__(256) void convtok_k(const float* __restrict__ tok,
                                                 u16* __restrict__ dst) {
  size_t r = blockIdx.x;
  int t = threadIdx.x;
  ushort4 w = {0, 0, 0, 0};
  if (r < NV) {
    float4 v = *(const float4*)(tok + r * DM + t * 4);
    w.x = f2b(v.x); w.y = f2b(v.y); w.z = f2b(v.z); w.w = f2b(v.w);
  }
  *(ushort4*)(dst + r * DM + t * 4) = w;
}

__global__ __launch_bounds__(256) void embed_k(const int* __restrict__ idx,
                                               const float* __restrict__ tok,
                                               const float* __restrict__ pos,
                                               float* __restrict__ x) {
  int row = blockIdx.x, t = threadIdx.x;
  int s = row & (SQ - 1);
  int id = idx[row];
  float4 a = *(const float4*)(tok + (size_t)id * DM + t * 4);
  float4 p = *(const float4*)(pos + (size_t)s * DM + t * 4);
  a.x += p.x; a.y += p.y; a.z += p.z; a.w += p.w;
  *(float4*)(x + (size_t)row * DM + t * 4) = a;
}

__global__ __launch_bounds__(256) void ln_k(const float* __restrict__ x,
                                            const float* __restrict__ sc,
                                            const float* __restrict__ sh,
                                            u16* __restrict__ o) {
  int row = blockIdx.x, t = threadIdx.x;
  const float* xr = x + (size_t)row * DM;
  float4 v = *(const float4*)(xr + t * 4);
  float s = v.x + v.y + v.z + v.w;
#pragma unroll
  for (int d = 32; d; d >>= 1) s += __shfl_xor(s, d);
  __shared__ float red[8];
  if ((t & 63) == 0) red[t >> 6] = s;
  __syncthreads();
  float mean = (red[0] + red[1] + red[2] + red[3]) * (1.f / DM);
  float dx = v.x - mean, dy = v.y - mean, dz = v.z - mean, dw = v.w - mean;
  float s2 = dx * dx + dy * dy + dz * dz + dw * dw;
#pragma unroll
  for (int d = 32; d; d >>= 1) s2 += __shfl_xor(s2, d);
  if ((t & 63) == 0) red[4 + (t >> 6)] = s2;
  __syncthreads();
  float var = (red[4] + red[5] + red[6] + red[7]) * (1.f / DM);
  float rstd = 1.f / sqrtf(var + 1e-6f);
  float4 g = *(const float4*)(sc + t * 4);
  float4 b = *(const float4*)(sh + t * 4);
  ushort4 w4;
  w4.x = f2b(g.x * (dx * rstd) + b.x);
  w4.y = f2b(g.y * (dy * rstd) + b.y);
  w4.z = f2b(g.z * (dz * rstd) + b.z);
  w4.w = f2b(g.w * (dw * rstd) + b.w);
  *(ushort4*)(o + (size_t)row * DM + t * 4) = w4;
}

extern "C" void kernel_launch(void* const* d_in, const int* in_sizes, int n_in,
                              void* d_out, int out_size, void* d_ws,
                              size_t ws_size, hipStream_t stream) {
  const int* idx = (const int*)d_in[0];
  const float* tok = (const float*)d_in[1];
  const float* pos = (const float*)d_in[2];
  const float* Wq = (const float*)d_in[3];
  const float* Wk = (const float*)d_in[4];
  const float* Wv = (const float*)d_in[5];
  const float* Wo = (const float*)d_in[6];
  const float* bo = (const float*)d_in[7];
  const float* W1 = (const float*)d_in[8];
  const float* b1 = (const float*)d_in[9];
  const float* W2 = (const float*)d_in[10];
  const float* b2 = (const float*)d_in[11];
  const float* ln1s = (const float*)d_in[12];
  const float* ln1b = (const float*)d_in[13];
  const float* ln2s = (const float*)d_in[14];
  const float* ln2b = (const float*)d_in[15];
  const float* lnfs = (const float*)d_in[16];
  const float* lnfb = (const float*)d_in[17];
  float* out = (float*)d_out;

  // workspace carve (~170 MB); cx aliases h (never simultaneously live)
  char* w = (char*)d_ws;
  float* x = (float*)w;  w += (size_t)MR * DM * 4;   // 8.4 MB
  u16* h = (u16*)w;      w += (size_t)MR * DM * 2;   // 4.2  (cx == h)
  u16* qb = (u16*)w;     w += (size_t)MR * DM * 2;   // 4.2
  u16* kb = (u16*)w;     w += (size_t)MR * DM * 2;   // 4.2
  u16* vt = (u16*)w;     w += (size_t)NB * DM * SQ * 2;  // 4.2
  u16* ff = (u16*)w;     w += (size_t)MR * DF * 2;   // 16.8
  u16* wb = (u16*)w;     w += ((size_t)4 * DM * DM + 2 * (size_t)DM * DF) * 2;
  u16* tokT = (u16*)w;   // 103 MB
  u16* cx = h;
  u16* wo_b = wb + (size_t)3 * DM * DM;
  u16* wb1 = wb + (size_t)4 * DM * DM;
  u16* wb2 = wb1 + (size_t)DM * DF;

  dim3 T(256);
  embed_k<<<MR, T, 0, stream>>>(idx, tok, pos, x);
  convtok_k<<<NVP, T, 0, stream>>>(tok, tokT);
  for (int l = 0; l < LL; ++l) {
    size_t wo_ = (size_t)l * DM * DM;
    size_t w1_ = (size_t)l * DM * DF;
    transpall_k<<<3072, T, 0, stream>>>(Wq + wo_, Wk + wo_, Wv + wo_, Wo + wo_,
                                        W1 + w1_, W2 + w1_, wb);
    ln_k<<<MR, T, 0, stream>>>(x, ln1s + l * DM, ln1b + l * DM, h);
    gemm_k<7, 128, 128, 4><<<384, T, 0, stream>>>(
        h, wb, qb, kb, vt, nullptr, 3 * DM, DM, DM, DM, DM);
    fattn_k<<<512, T, 0, stream>>>(qb, kb, vt, cx);
    gemm_k<1, 64, 128, 5><<<256, T, 0, stream>>>(
        cx, wo_b, x, nullptr, nullptr, bo + l * DM, DM, DM, DM, DM, DM);
    ln_k<<<MR, T, 0, stream>>>(x, ln2s + l * DM, ln2b + l * DM, h);
    gemm_k<2, 128, 128, 4><<<512, T, 0, stream>>>(
        h, wb1, ff, nullptr, nullptr, b1 + l * DF, DF, DM, DM, DM, DF);
    gemm_k<1, 64, 128, 5><<<256, T, 0, stream>>>(
        ff, wb2, x, nullptr, nullptr, b2 + l * DM, DM, DF, DF, DF, DM);
  }
  ln_k<<<MR, T, 0, stream>>>(x, lnfs, lnfb, h);
  gemm_k<6, 128, 128, 4><<<6288, T, 0, stream>>>(
      h, tokT, out, nullptr, nullptr, nullptr, NV, DM, DM, DM, NV);
}

// Round 4
// 2285.079 us; speedup vs baseline: 3.1771x; 1.2736x over previous
//
#include <hip/hip_runtime.h>

// GPT-2 forward. Round 4: 2-phase pipelined GEMM (double-buffered LDS, BK=64,
// prefetch-before-compute, 1 barrier/K-step), stage-side XOR swizzle for
// conflict-free ds_read_b128, grid-filling tiles, merged small launches.

#define LL 12
#define DM 1024
#define NH 16
#define DHD 64
#define NV 50257
#define NVP 50304
#define SQ 512
#define NB 4
#define DF 4096
#define MR (NB * SQ)

typedef short bf16x8 __attribute__((ext_vector_type(8)));
typedef float f32x4 __attribute__((ext_vector_type(4)));
typedef unsigned short u16;

__device__ __forceinline__ u16 f2b(float f) {  // f32 -> bf16 RNE
  unsigned u = __float_as_uint(f);
  u += 0x7fff + ((u >> 16) & 1);
  return (u16)(u >> 16);
}

__device__ __forceinline__ void gload16(const u16* g, u16* l) {
  __builtin_amdgcn_global_load_lds(
      (const __attribute__((address_space(1))) unsigned*)g,
      (__attribute__((address_space(3))) unsigned*)l, 16, 0, 0);
}

// ---------------- GEMM: C[M,N] = A[M,K](bf16) @ B[N,K](bf16)^T --------------
// MODE 1: Cf32 += acc + bias   MODE 2: bf16 C = gelu(acc+bias)
// MODE 6: logits f32, n<NV     MODE 7: QKV fused (route n>>10), V transposed
// 2-phase pipeline: stage(kt+1) issued before compute(kt); 1 barrier/K-step.
// LDS linear [rows][64], global source pre-swizzled so swizzled reads are
// conflict-free (rule #21: both-sides-or-neither).
template <int MODE, int TBM, int TBN, int MTLOG>
__global__ __launch_bounds__(256, 2) void gemm_k(
    const u16* __restrict__ A, const u16* __restrict__ B, void* __restrict__ Cp,
    void* __restrict__ Cp2, void* __restrict__ Cp3,
    const float* __restrict__ bias, int N, int K, int lda, int ldb, int ldc) {
  int id = blockIdx.x;
  int q8 = gridDim.x >> 3;
  int swz = (id & 7) * q8 + (id >> 3);
  int mt = swz & ((1 << MTLOG) - 1), nt = swz >> MTLOG;
  int m0 = mt * TBM, n0 = nt * TBN;

  __shared__ u16 As[2][TBM * 64];
  __shared__ u16 Bs[2][TBN * 64];

  int t = threadIdx.x, lane = t & 63, wave = t >> 6;
  int wm = wave >> 1, wn = wave & 1;
  int lr = lane & 15, g = lane >> 4;
  int srow = lane >> 3;
  int sxcol = ((lane & 7) ^ (lane >> 3)) << 3;  // inverse-swizzled global col
  int rsw = (lr & 7) << 3;                      // read-side XOR (u16 units)
  constexpr int FM = TBM / 32, FN = TBN / 32;
  constexpr int CA = TBM / 32, CB = TBN / 32;  // 8-row chunks per wave

  f32x4 acc[FM][FN];
#pragma unroll
  for (int i = 0; i < FM; ++i)
#pragma unroll
    for (int j = 0; j < FN; ++j) acc[i][j] = (f32x4){0.f, 0.f, 0.f, 0.f};

  auto stage = [&](int buf, int kt) {
    int k0 = kt * 64;
#pragma unroll
    for (int v = 0; v < CA; ++v) {
      int c = v * 4 + wave;
      gload16(A + (size_t)(m0 + c * 8 + srow) * lda + k0 + sxcol,
              &As[buf][c * 512]);
    }
#pragma unroll
    for (int v = 0; v < CB; ++v) {
      int c = v * 4 + wave;
      gload16(B + (size_t)(n0 + c * 8 + srow) * ldb + k0 + sxcol,
              &Bs[buf][c * 512]);
    }
  };

  auto compute = [&](int buf) {
    bf16x8 af[FM][2], bq[FN][2];
#pragma unroll
    for (int ks = 0; ks < 2; ++ks) {
      int co = (ks * 32 + g * 8) ^ rsw;
#pragma unroll
      for (int i = 0; i < FM; ++i)
        af[i][ks] = *(const bf16x8*)&As[buf][(wm * (TBM / 2) + i * 16 + lr) * 64 + co];
#pragma unroll
      for (int j = 0; j < FN; ++j)
        bq[j][ks] = *(const bf16x8*)&Bs[buf][(wn * (TBN / 2) + j * 16 + lr) * 64 + co];
    }
#pragma unroll
    for (int ks = 0; ks < 2; ++ks)
#pragma unroll
      for (int i = 0; i < FM; ++i)
#pragma unroll
        for (int j = 0; j < FN; ++j)
          acc[i][j] = __builtin_amdgcn_mfma_f32_16x16x32_bf16(
              af[i][ks], bq[j][ks], acc[i][j], 0, 0, 0);
  };

  int nk = K >> 6;
  stage(0, 0);
  __syncthreads();
  int cur = 0;
  for (int kt = 0; kt < nk - 1; ++kt) {
    stage(cur ^ 1, kt + 1);  // prefetch next tile; latency hides under MFMA
    compute(cur);
    __syncthreads();         // drains vmcnt(0): next tile staged, cur tile read
    cur ^= 1;
  }
  compute(cur);

  // epilogue (C/D frag: col = lane&15, row = (lane>>4)*4 + r)
  int rb = g * 4;
#pragma unroll
  for (int i = 0; i < FM; ++i) {
#pragma unroll
    for (int j = 0; j < FN; ++j) {
      int m = m0 + wm * (TBM / 2) + i * 16 + rb;
      int n = n0 + wn * (TBN / 2) + j * 16 + lr;
      f32x4 a = acc[i][j];
      if constexpr (MODE == 1) {
        float* C = (float*)Cp;
        float bv = bias[n];
#pragma unroll
        for (int r = 0; r < 4; ++r) {
          size_t ix = (size_t)(m + r) * ldc + n;
          C[ix] += a[r] + bv;
        }
      } else if constexpr (MODE == 2) {
        u16* C = (u16*)Cp;
        float bv = bias[n];
#pragma unroll
        for (int r = 0; r < 4; ++r) {
          float u2 = a[r] + bv;
          float gl =
              0.5f * u2 *
              (1.f + tanhf(0.7978845608f * (u2 + 0.044715f * u2 * u2 * u2)));
          C[(size_t)(m + r) * ldc + n] = f2b(gl);
        }
      } else if constexpr (MODE == 6) {
        if (n < NV) {
          float* C = (float*)Cp;
#pragma unroll
          for (int r = 0; r < 4; ++r) C[(size_t)(m + r) * ldc + n] = a[r];
        }
      } else if constexpr (MODE == 7) {
        int sel = n >> 10, nn = n & 1023;
        if (sel < 2) {
          u16* C = sel == 0 ? (u16*)Cp : (u16*)Cp2;
#pragma unroll
          for (int r = 0; r < 4; ++r) C[(size_t)(m + r) * ldc + nn] = f2b(a[r]);
        } else {  // V transposed: vt[b][d][s]
          u16* C = (u16*)Cp3;
          int bb = m >> 9, s2 = m & (SQ - 1);
          ushort4 w4;
          w4.x = f2b(a[0]); w4.y = f2b(a[1]);
          w4.z = f2b(a[2]); w4.w = f2b(a[3]);
          *(ushort4*)&C[((size_t)bb * DM + nn) * SQ + s2] = w4;
        }
      }
    }
  }
}

// -------- flash attention: one block = (qt 64 q-rows, b,h); 4 waves ---------
__global__ __launch_bounds__(256) void fattn_k(const u16* __restrict__ qb,
                                               const u16* __restrict__ kb,
                                               const u16* __restrict__ vt,
                                               u16* __restrict__ cx) {
  int id = blockIdx.x;
  int qt = id >> 6, bh = id & 63;
  int b = bh >> 4, hh = bh & 15;
  int t = threadIdx.x, lane = t & 63, w = t >> 6;
  int lr = lane & 15, g = lane >> 4;

  __shared__ u16 Kt[64 * 72];
  __shared__ u16 Vt[64 * 72];
  __shared__ u16 Pl[4 * 16 * 72];

  int qw = qt * 64 + w * 16;

  bf16x8 aQ[2];
#pragma unroll
  for (int f = 0; f < 2; ++f)
    aQ[f] = *(const bf16x8*)&qb[(size_t)(b * SQ + qw + lr) * DM + hh * DHD +
                                f * 32 + g * 8];

  f32x4 o[4];
#pragma unroll
  for (int j = 0; j < 4; ++j) o[j] = (f32x4){0.f, 0.f, 0.f, 0.f};
  f32x4 m4 = (f32x4){-3e38f, -3e38f, -3e38f, -3e38f};
  f32x4 l4 = (f32x4){0.f, 0.f, 0.f, 0.f};
  u16* Pw = &Pl[w * 16 * 72];

  for (int kt = 0; kt <= qt; ++kt) {
    int k0 = kt * 64;
#pragma unroll
    for (int it = 0; it < 2; ++it) {
      int c = t + it * 256;
      int row = c >> 3, ch = c & 7;
      int4 kv = *(const int4*)&kb[(size_t)(b * SQ + k0 + row) * DM + hh * DHD +
                                  ch * 8];
      int4 vv = *(const int4*)&vt[(size_t)(b * DM + hh * DHD + row) * SQ + k0 +
                                  ch * 8];
      *(int4*)&Kt[row * 72 + ch * 8] = kv;
      *(int4*)&Vt[row * 72 + ch * 8] = vv;
    }
    __syncthreads();

    f32x4 s[4];
#pragma unroll
    for (int j = 0; j < 4; ++j) s[j] = (f32x4){0.f, 0.f, 0.f, 0.f};
#pragma unroll
    for (int j = 0; j < 4; ++j)
#pragma unroll
      for (int f = 0; f < 2; ++f) {
        bf16x8 bk = *(const bf16x8*)&Kt[(j * 16 + lr) * 72 + f * 32 + g * 8];
        s[j] =
            __builtin_amdgcn_mfma_f32_16x16x32_bf16(aQ[f], bk, s[j], 0, 0, 0);
      }
#pragma unroll
    for (int j = 0; j < 4; ++j) {
      int kcol = k0 + j * 16 + lr;
#pragma unroll
      for (int r = 0; r < 4; ++r) {
        float sv = s[j][r] * 0.125f;
        if (kt == qt && kcol > qw + g * 4 + r) sv = -1e30f;
        s[j][r] = sv;
      }
    }
    f32x4 fr;
#pragma unroll
    for (int r = 0; r < 4; ++r) {
      float v = fmaxf(fmaxf(s[0][r], s[1][r]), fmaxf(s[2][r], s[3][r]));
#pragma unroll
      for (int d = 1; d < 16; d <<= 1) v = fmaxf(v, __shfl_xor(v, d));
      float mn = fmaxf(m4[r], v);
      fr[r] = __expf(m4[r] - mn);
      m4[r] = mn;
    }
#pragma unroll
    for (int j = 0; j < 4; ++j)
#pragma unroll
      for (int r = 0; r < 4; ++r) o[j][r] *= fr[r];
    f32x4 ps = (f32x4){0.f, 0.f, 0.f, 0.f};
#pragma unroll
    for (int j = 0; j < 4; ++j)
#pragma unroll
      for (int r = 0; r < 4; ++r) {
        float p = __expf(s[j][r] - m4[r]);
        s[j][r] = p;
        ps[r] += p;
      }
#pragma unroll
    for (int r = 0; r < 4; ++r) {
      float v = ps[r];
#pragma unroll
      for (int d = 1; d < 16; d <<= 1) v += __shfl_xor(v, d);
      l4[r] = l4[r] * fr[r] + v;
    }
#pragma unroll
    for (int j = 0; j < 4; ++j)
#pragma unroll
      for (int r = 0; r < 4; ++r)
        Pw[(g * 4 + r) * 72 + j * 16 + lr] = f2b(s[j][r]);
#pragma unroll
    for (int f = 0; f < 2; ++f) {
      bf16x8 ap = *(const bf16x8*)&Pw[lr * 72 + f * 32 + g * 8];
#pragma unroll
      for (int j = 0; j < 4; ++j) {
        bf16x8 bv = *(const bf16x8*)&Vt[(j * 16 + lr) * 72 + f * 32 + g * 8];
        o[j] = __builtin_amdgcn_mfma_f32_16x16x32_bf16(ap, bv, o[j], 0, 0, 0);
      }
    }
    __syncthreads();
  }

#pragma unroll
  for (int r = 0; r < 4; ++r) {
    float inv = 1.f / l4[r];
#pragma unroll
    for (int j = 0; j < 4; ++j)
      cx[(size_t)(b * SQ + qw + g * 4 + r) * DM + hh * DHD + j * 16 + lr] =
          f2b(o[j][r] * inv);
  }
}

// ---- merged: weight transpose (blocks 0..3071) + ln1 (blocks 3072..5119) ---
__global__ __launch_bounds__(256) void transpln_k(
    const float* __restrict__ Wq, const float* __restrict__ Wk,
    const float* __restrict__ Wv, const float* __restrict__ Wo,
    const float* __restrict__ W1, const float* __restrict__ W2,
    u16* __restrict__ wb, const float* __restrict__ x,
    const float* __restrict__ sc, const float* __restrict__ sh,
    u16* __restrict__ o) {
  __shared__ u16 tl[64][72];
  __shared__ float red[8];
  int t = threadIdx.x;
  if (blockIdx.x < 3072) {
    int id = blockIdx.x;
    const float* src;
    u16* dst;
    int K, N, ktile, ntile;
    if (id < 1024) {
      int mat = id >> 8, rem = id & 255;
      ntile = rem & 15; ktile = rem >> 4;
      src = mat == 0 ? Wq : mat == 1 ? Wk : mat == 2 ? Wv : Wo;
      dst = wb + (size_t)mat * DM * DM;
      K = DM; N = DM;
    } else if (id < 2048) {
      int rem = id - 1024;
      ntile = rem & 63; ktile = rem >> 6;
      src = W1; dst = wb + (size_t)4 * DM * DM;
      K = DM; N = DF;
    } else {
      int rem = id - 2048;
      ntile = rem & 15; ktile = rem >> 4;
      src = W2; dst = wb + (size_t)4 * DM * DM + (size_t)DM * DF;
      K = DF; N = DM;
    }
    int n0 = ntile * 64, k0 = ktile * 64;
    int tn = (t & 15) * 4, tk = t >> 4;
#pragma unroll
    for (int it = 0; it < 4; ++it) {
      int k = tk + it * 16;
      float4 v = *(const float4*)(src + (size_t)(k0 + k) * N + n0 + tn);
      tl[tn + 0][k] = f2b(v.x);
      tl[tn + 1][k] = f2b(v.y);
      tl[tn + 2][k] = f2b(v.z);
      tl[tn + 3][k] = f2b(v.w);
    }
    __syncthreads();
    int wn = t >> 3, wk = (t & 7) * 8;
#pragma unroll
    for (int it = 0; it < 2; ++it) {
      int n = wn + it * 32;
      int4 v = *(const int4*)&tl[n][wk];
      *(int4*)(dst + (size_t)(n0 + n) * K + k0 + wk) = v;
    }
  } else {
    int row = blockIdx.x - 3072;
    const float* xr = x + (size_t)row * DM;
    float4 v = *(const float4*)(xr + t * 4);
    float s = v.x + v.y + v.z + v.w;
#pragma unroll
    for (int d = 32; d; d >>= 1) s += __shfl_xor(s, d);
    if ((t & 63) == 0) red[t >> 6] = s;
    __syncthreads();
    float mean = (red[0] + red[1] + red[2] + red[3]) * (1.f / DM);
    float dx = v.x - mean, dy = v.y - mean, dz = v.z - mean, dw = v.w - mean;
    float s2 = dx * dx + dy * dy + dz * dz + dw * dw;
#pragma unroll
    for (int d = 32; d; d >>= 1) s2 += __shfl_xor(s2, d);
    if ((t & 63) == 0) red[4 + (t >> 6)] = s2;
    __syncthreads();
    float var = (red[4] + red[5] + red[6] + red[7]) * (1.f / DM);
    float rstd = 1.f / sqrtf(var + 1e-6f);
    float4 gg = *(const float4*)(sc + t * 4);
    float4 b = *(const float4*)(sh + t * 4);
    ushort4 w4;
    w4.x = f2b(gg.x * (dx * rstd) + b.x);
    w4.y = f2b(gg.y * (dy * rstd) + b.y);
    w4.z = f2b(gg.z * (dz * rstd) + b.z);
    w4.w = f2b(gg.w * (dw * rstd) + b.w);
    *(ushort4*)(o + (size_t)row * DM + t * 4) = w4;
  }
}

__global__ __launch_bounds__(256) void ln_k(const float* __restrict__ x,
                                            const float* __restrict__ sc,
                                            const float* __restrict__ sh,
                                            u16* __restrict__ o) {
  int row = blockIdx.x, t = threadIdx.x;
  const float* xr = x + (size_t)row * DM;
  float4 v = *(const float4*)(xr + t * 4);
  float s = v.x + v.y + v.z + v.w;
#pragma unroll
  for (int d = 32; d; d >>= 1) s += __shfl_xor(s, d);
  __shared__ float red[8];
  if ((t & 63) == 0) red[t >> 6] = s;
  __syncthreads();
  float mean = (red[0] + red[1] + red[2] + red[3]) * (1.f / DM);
  float dx = v.x - mean, dy = v.y - mean, dz = v.z - mean, dw = v.w - mean;
  float s2 = dx * dx + dy * dy + dz * dz + dw * dw;
#pragma unroll
  for (int d = 32; d; d >>= 1) s2 += __shfl_xor(s2, d);
  if ((t & 63) == 0) red[4 + (t >> 6)] = s2;
  __syncthreads();
  float var = (red[4] + red[5] + red[6] + red[7]) * (1.f / DM);
  float rstd = 1.f / sqrtf(var + 1e-6f);
  float4 g = *(const float4*)(sc + t * 4);
  float4 b = *(const float4*)(sh + t * 4);
  ushort4 w4;
  w4.x = f2b(g.x * (dx * rstd) + b.x);
  w4.y = f2b(g.y * (dy * rstd) + b.y);
  w4.z = f2b(g.z * (dz * rstd) + b.z);
  w4.w = f2b(g.w * (dw * rstd) + b.w);
  *(ushort4*)(o + (size_t)row * DM + t * 4) = w4;
}

// merged: embed (blocks 0..MR-1) + tok_emb bf16 conversion (rest)
__global__ __launch_bounds__(256) void embtok_k(const int* __restrict__ idx,
                                                const float* __restrict__ tok,
                                                const float* __restrict__ pos,
                                                float* __restrict__ x,
                                                u16* __restrict__ tokT) {
  int t = threadIdx.x;
  if (blockIdx.x < MR) {
    int row = blockIdx.x;
    int s = row & (SQ - 1);
    int id = idx[row];
    float4 a = *(const float4*)(tok + (size_t)id * DM + t * 4);
    float4 p = *(const float4*)(pos + (size_t)s * DM + t * 4);
    a.x += p.x; a.y += p.y; a.z += p.z; a.w += p.w;
    *(float4*)(x + (size_t)row * DM + t * 4) = a;
  } else {
    size_t r = blockIdx.x - MR;
    ushort4 w = {0, 0, 0, 0};
    if (r < NV) {
      float4 v = *(const float4*)(tok + r * DM + t * 4);
      w.x = f2b(v.x); w.y = f2b(v.y); w.z = f2b(v.z); w.w = f2b(v.w);
    }
    *(ushort4*)(tokT + r * DM + t * 4) = w;
  }
}

extern "C" void kernel_launch(void* const* d_in, const int* in_sizes, int n_in,
                              void* d_out, int out_size, void* d_ws,
                              size_t ws_size, hipStream_t stream) {
  const int* idx = (const int*)d_in[0];
  const float* tok = (const float*)d_in[1];
  const float* pos = (const float*)d_in[2];
  const float* Wq = (const float*)d_in[3];
  const float* Wk = (const float*)d_in[4];
  const float* Wv = (const float*)d_in[5];
  const float* Wo = (const float*)d_in[6];
  const float* bo = (const float*)d_in[7];
  const float* W1 = (const float*)d_in[8];
  const float* b1 = (const float*)d_in[9];
  const float* W2 = (const float*)d_in[10];
  const float* b2 = (const float*)d_in[11];
  const float* ln1s = (const float*)d_in[12];
  const float* ln1b = (const float*)d_in[13];
  const float* ln2s = (const float*)d_in[14];
  const float* ln2b = (const float*)d_in[15];
  const float* lnfs = (const float*)d_in[16];
  const float* lnfb = (const float*)d_in[17];
  float* out = (float*)d_out;

  char* w = (char*)d_ws;
  float* x = (float*)w;  w += (size_t)MR * DM * 4;
  u16* h = (u16*)w;      w += (size_t)MR * DM * 2;
  u16* qb = (u16*)w;     w += (size_t)MR * DM * 2;
  u16* kb = (u16*)w;     w += (size_t)MR * DM * 2;
  u16* vt = (u16*)w;     w += (size_t)NB * DM * SQ * 2;
  u16* ff = (u16*)w;     w += (size_t)MR * DF * 2;
  u16* wb = (u16*)w;     w += ((size_t)4 * DM * DM + 2 * (size_t)DM * DF) * 2;
  u16* tokT = (u16*)w;
  u16* cx = h;
  u16* wo_b = wb + (size_t)3 * DM * DM;
  u16* wb1 = wb + (size_t)4 * DM * DM;
  u16* wb2 = wb1 + (size_t)DM * DF;

  dim3 T(256);
  embtok_k<<<MR + NVP, T, 0, stream>>>(idx, tok, pos, x, tokT);
  for (int l = 0; l < LL; ++l) {
    size_t wo_ = (size_t)l * DM * DM;
    size_t w1_ = (size_t)l * DM * DF;
    transpln_k<<<5120, T, 0, stream>>>(Wq + wo_, Wk + wo_, Wv + wo_, Wo + wo_,
                                       W1 + w1_, W2 + w1_, wb, x, ln1s + l * DM,
                                       ln1b + l * DM, h);
    gemm_k<7, 64, 128, 5><<<768, T, 0, stream>>>(
        h, wb, qb, kb, vt, nullptr, 3 * DM, DM, DM, DM, DM);
    fattn_k<<<512, T, 0, stream>>>(qb, kb, vt, cx);
    gemm_k<1, 64, 64, 5><<<512, T, 0, stream>>>(
        cx, wo_b, x, nullptr, nullptr, bo + l * DM, DM, DM, DM, DM, DM);
    ln_k<<<MR, T, 0, stream>>>(x, ln2s + l * DM, ln2b + l * DM, h);
    gemm_k<2, 128, 128, 4><<<512, T, 0, stream>>>(
        h, wb1, ff, nullptr, nullptr, b1 + l * DF, DF, DM, DM, DM, DF);
    gemm_k<1, 64, 64, 5><<<512, T, 0, stream>>>(
        ff, wb2, x, nullptr, nullptr, b2 + l * DM, DM, DF, DF, DF, DM);
  }
  ln_k<<<MR, T, 0, stream>>>(x, lnfs, lnfb, h);
  gemm_k<6, 128, 128, 4><<<6288, T, 0, stream>>>(
      h, tokT, out, nullptr, nullptr, nullptr, NV, DM, DM, DM, NV);
}